// Round 3
// baseline (332.482 us; speedup 1.0000x reference)
//
#include <hip/hip_runtime.h>

#define NUM_C 512
#define HW    32768     // 128*256
#define K     19
#define NT    256
#define CP    (NUM_C + 4)   // padded LDS row stride (float4-aligned; 3-way bank alias max)

// ---------------------------------------------------------------------------
// K1: per-(b,c)-plane segment sums. grid = 1024 blocks x 256 threads.
// __launch_bounds__(256,4): VGPR cap 128 so accS/accT (38 floats) stay in
// VGPRs (R2's (256) default capped at 36 VGPR -> AGPR/scratch RMW = 3x VALU).
// Grid is 4 blocks/CU = 4 waves/EU, so min-waves=4 costs no occupancy.
// ---------------------------------------------------------------------------
__global__ __launch_bounds__(NT, 4) void seg_sum_kernel(
    const float* __restrict__ S, const float* __restrict__ T,
    const int* __restrict__ lbl,
    float* __restrict__ sumsS, float* __restrict__ sumsT,
    float* __restrict__ out)
{
    const int tid   = threadIdx.x;
    const int plane = blockIdx.x;        // b*512 + c
    const int b     = plane >> 9;

    if (plane == 0 && tid == 0) out[0] = 0.f;   // zero-init for K2's atomicAdd

    const float4* S4 = (const float4*)(S + (size_t)plane * HW);
    const float4* T4 = (const float4*)(T + (size_t)plane * HW);
    const int4*   L4 = (const int4*)(lbl + (size_t)b * HW);

    float accS[K], accT[K];
#pragma unroll
    for (int k = 0; k < K; ++k) { accS[k] = 0.f; accT[k] = 0.f; }

    for (int i = tid; i < HW / 4; i += NT) {
        float4 s = S4[i];
        float4 t = T4[i];
        int4   l = L4[i];
#pragma unroll
        for (int k = 0; k < K; ++k) {
            float m;
            m = (l.x == k) ? 1.f : 0.f; accS[k] = fmaf(m, s.x, accS[k]); accT[k] = fmaf(m, t.x, accT[k]);
            m = (l.y == k) ? 1.f : 0.f; accS[k] = fmaf(m, s.y, accS[k]); accT[k] = fmaf(m, t.y, accT[k]);
            m = (l.z == k) ? 1.f : 0.f; accS[k] = fmaf(m, s.z, accS[k]); accT[k] = fmaf(m, t.z, accT[k]);
            m = (l.w == k) ? 1.f : 0.f; accS[k] = fmaf(m, s.w, accS[k]); accT[k] = fmaf(m, t.w, accT[k]);
        }
    }

    // cross-thread reduce: wave shuffle (6 steps) -> LDS (4 waves) -> global
    __shared__ float redS[4 * K], redT[4 * K];
    const int lane = tid & 63, wv = tid >> 6;
#pragma unroll
    for (int k = 0; k < K; ++k) {
        float vs = accS[k], vt = accT[k];
#pragma unroll
        for (int off = 32; off > 0; off >>= 1) {
            vs += __shfl_down(vs, off);
            vt += __shfl_down(vt, off);
        }
        if (lane == 0) { redS[wv * K + k] = vs; redT[wv * K + k] = vt; }
    }
    __syncthreads();
    if (tid < K) {
        sumsS[(size_t)plane * K + tid] = redS[tid] + redS[K + tid] + redS[2 * K + tid] + redS[3 * K + tid];
        sumsT[(size_t)plane * K + tid] = redT[tid] + redT[K + tid] + redT[2 * K + tid] + redT[3 * K + tid];
    }
}

// ---------------------------------------------------------------------------
// K2: grid = 8 blocks = 2 batches x 4 slices. Each block redundantly builds
// counts + centers + diagonal norms (cheap), then handles ~180 of the 722
// (matrix,i,j) dot tasks, normalizing inline via the precomputed norms and
// accumulating (cosS - cosT)^2 directly. One atomicAdd per block.
// ---------------------------------------------------------------------------
__global__ __launch_bounds__(NT, 4) void finalize_kernel(
    const float* __restrict__ sumsS, const float* __restrict__ sumsT,
    const int* __restrict__ lbl, float* __restrict__ out)
{
    __shared__ float centS[K * CP];
    __shared__ float centT[K * CP];
    __shared__ float cntf[K];
    __shared__ float nrm[2 * K];     // ||c_k||, S then T
    __shared__ float red[NT];
    __shared__ int   redc[4 * K];
    const int tid   = threadIdx.x;
    const int b     = blockIdx.x >> 2;
    const int slice = blockIdx.x & 3;

    // ---- exact label counts in registers (branchless) ----
    int cnt[K];
#pragma unroll
    for (int k = 0; k < K; ++k) cnt[k] = 0;
    const int4* L4 = (const int4*)(lbl + (size_t)b * HW);
    for (int i = tid; i < HW / 4; i += NT) {
        int4 l = L4[i];
#pragma unroll
        for (int k = 0; k < K; ++k)
            cnt[k] += (l.x == k) + (l.y == k) + (l.z == k) + (l.w == k);
    }
    const int lane = tid & 63, wv = tid >> 6;
#pragma unroll
    for (int k = 0; k < K; ++k) {
        int v = cnt[k];
#pragma unroll
        for (int off = 32; off > 0; off >>= 1) v += __shfl_down(v, off);
        if (lane == 0) redc[wv * K + k] = v;
    }
    __syncthreads();
    if (tid < K)
        cntf[tid] = (float)(redc[tid] + redc[K + tid] + redc[2 * K + tid] + redc[3 * K + tid]) + 1e-6f;
    __syncthreads();

    // ---- centers: [k][c] layout, padded stride ----
    for (int j = tid; j < NUM_C * K; j += NT) {
        int c = j / K, k = j - c * K;
        float cn = cntf[k];
        size_t gi = ((size_t)b * NUM_C + c) * K + k;
        centS[k * CP + c] = sumsS[gi] / cn;
        centT[k * CP + c] = sumsT[gi] / cn;
    }
    __syncthreads();

    // ---- diagonal norms (38 tasks) ----
    if (tid < 2 * K) {
        const float4* A = (const float4*)((tid < K ? centS : centT) + (tid < K ? tid : tid - K) * CP);
        float d = 0.f;
        for (int c = 0; c < NUM_C / 4; ++c) {
            float4 x = A[c];
            d = fmaf(x.x, x.x, d); d = fmaf(x.y, x.y, d);
            d = fmaf(x.z, x.z, d); d = fmaf(x.w, x.w, d);
        }
        nrm[tid] = fmaxf(sqrtf(d), 1e-8f);
    }
    __syncthreads();

    // ---- dot tasks: t in [0,1024), interleaved over slices; 722 real ----
    float acc = 0.f;
    int t = tid * 4 + slice;
    if (t < 2 * K * K) {
        int a  = t / (K * K);            // 0 = S, 1 = T ... need both! decode as pair index
        int ij = t - a * (K * K);
        int i  = ij / K, j = ij - (ij / K) * K;
        // compute BOTH dots for this (i,j) when a==0; when a==1 compute the
        // same pair's dots too would duplicate -- instead: a==0 -> S, a==1 -> T
        // but the loss needs the difference. So: decode t as pure (i,j) over
        // 361 pairs, and each task computes both dots. t >= 361 is idle.
        (void)a; (void)ij; (void)i; (void)j;
    }
    // Simpler balanced decode: 361 pair-tasks, each does both dots.
    t = tid * 4 + slice;
    if (t < K * K) {
        int i = t / K, j = t - (t / K) * K;
        const float4* Si = (const float4*)(centS + i * CP);
        const float4* Sj = (const float4*)(centS + j * CP);
        const float4* Ti = (const float4*)(centT + i * CP);
        const float4* Tj = (const float4*)(centT + j * CP);
        float ds = 0.f, dt = 0.f;
        for (int c = 0; c < NUM_C / 4; ++c) {
            float4 xs = Si[c], ys = Sj[c];
            float4 xt = Ti[c], yt = Tj[c];
            ds = fmaf(xs.x, ys.x, ds); ds = fmaf(xs.y, ys.y, ds);
            ds = fmaf(xs.z, ys.z, ds); ds = fmaf(xs.w, ys.w, ds);
            dt = fmaf(xt.x, yt.x, dt); dt = fmaf(xt.y, yt.y, dt);
            dt = fmaf(xt.z, yt.z, dt); dt = fmaf(xt.w, yt.w, dt);
        }
        float d = ds / (nrm[i] * nrm[j]) - dt / (nrm[K + i] * nrm[K + j]);
        acc = d * d;
    }

    red[tid] = acc;
    __syncthreads();
    for (int s = NT / 2; s > 0; s >>= 1) {
        if (tid < s) red[tid] += red[tid + s];
        __syncthreads();
    }
    if (tid == 0 && red[0] != 0.f)
        atomicAdd(out, red[0] * (1.0f / (2.0f * K * K)));  // mean over [B,K,K]
    else if (tid == 0)
        atomicAdd(out, 0.f);   // keep op count uniform (no-op, safe)
}

extern "C" void kernel_launch(void* const* d_in, const int* in_sizes, int n_in,
                              void* d_out, int out_size, void* d_ws, size_t ws_size,
                              hipStream_t stream) {
    const float* S   = (const float*)d_in[0];   // preds_S  [2,512,128,256] fp32
    const float* T   = (const float*)d_in[1];   // preds_T  [2,512,128,256] fp32
    const int*   lbl = (const int*)d_in[2];     // target   [2,1,128,256] int32
    float* out = (float*)d_out;

    float* sumsS = (float*)d_ws;                 // [1024*19]
    float* sumsT = sumsS + (size_t)2 * NUM_C * K;

    seg_sum_kernel<<<2 * NUM_C, NT, 0, stream>>>(S, T, lbl, sumsS, sumsT, out);
    finalize_kernel<<<8, NT, 0, stream>>>(sumsS, sumsT, lbl, out);
}